// Round 3
// baseline (4804.553 us; speedup 1.0000x reference)
//
#include <hip/hip_runtime.h>
#include <math.h>
#include <stdint.h>

// Problem constants (from reference)
#define NN   10000      // nodes
#define EE   160000     // edges
#define BB   32         // batch
#define FDIM 384        // K*(DIM_IN+DIM_OUT) = 3*128

// ---------------- CSR build ----------------

__global__ void count_kernel(const int* __restrict__ ei, int* __restrict__ counts) {
    int e = blockIdx.x * blockDim.x + threadIdx.x;
    if (e < EE) atomicAdd(&counts[ei[e]], 1);
}

__global__ void scan_kernel(const int* __restrict__ counts, int* __restrict__ row_ptr) {
    __shared__ int sh[1024];
    int t = threadIdx.x;
    const int CH = 10;                       // 1024*10 >= NN
    int base = t * CH;
    int local[CH];
    int s = 0;
#pragma unroll
    for (int i = 0; i < CH; i++) {
        int idx = base + i;
        int v = (idx < NN) ? counts[idx] : 0;
        local[i] = v; s += v;
    }
    sh[t] = s;
    __syncthreads();
    for (int off = 1; off < 1024; off <<= 1) {
        int add = (t >= off) ? sh[t - off] : 0;
        __syncthreads();
        sh[t] += add;
        __syncthreads();
    }
    int prefix = (t == 0) ? 0 : sh[t - 1];
#pragma unroll
    for (int i = 0; i < CH; i++) {
        int idx = base + i;
        if (idx < NN) row_ptr[idx] = prefix;
        prefix += local[i];
    }
    if (t == 1023) row_ptr[NN] = prefix;     // == EE
}

__global__ void fill_kernel(const int* __restrict__ ei, const float* __restrict__ ew,
                            const int* __restrict__ row_ptr, int* __restrict__ cursor,
                            int* __restrict__ col_s, float* __restrict__ w_s) {
    int e = blockIdx.x * blockDim.x + threadIdx.x;
    if (e < EE) {
        int r = ei[e];
        int c = ei[EE + e];
        int pos = row_ptr[r] + atomicAdd(&cursor[r], 1);
        col_s[pos] = c;
        w_s[pos] = ew[e];
    }
}

// ---------------- SpMM (CSR row-gather), fp32 ----------------
// out[b,n,f] = alpha * sum_j w_j * src[b,col_j,f]   (- sub[b,n,f] if sub)
// f<64 -> srcA (stride strideA), f>=64 -> srcB (stride strideB)
__global__ __launch_bounds__(256)
void spmm_gather(const int* __restrict__ row_ptr,
                 const int* __restrict__ col_s,
                 const float* __restrict__ w_s,
                 const float* __restrict__ srcA, int strideA,
                 const float* __restrict__ srcB, int strideB,
                 const float* __restrict__ subA,
                 const float* __restrict__ subB,
                 float alpha,
                 float* __restrict__ outbuf) {
    int b    = blockIdx.y;
    int node = blockIdx.x * 2 + (threadIdx.x >> 7);
    int f    = threadIdx.x & 127;
    int start = row_ptr[node], end = row_ptr[node + 1];
    const float* src; int stride; int fo;
    if (f < 64) { src = srcA; stride = strideA; fo = f; }
    else        { src = srcB; stride = strideB; fo = f - 64; }
    long base = (long)b * NN;
    float acc = 0.f;
    for (int j = start; j < end; ++j) {
        int c = col_s[j];
        acc += w_s[j] * src[(base + c) * (long)stride + fo];
    }
    float v = alpha * acc;
    if (subA) {
        const float* sub = (f < 64) ? subA : subB;
        v -= sub[(base + node) * 64 + fo];
    }
    outbuf[(base + node) * 128 + f] = v;
}

// ---------------- GEMM over virtual x_diff = [x0 | W1 | W2] ----------------
// MODE 0: NOUT=128 gates -> z, rh = sigmoid(r)*hx
// MODE 1: NOUT=64 candidate -> out = (1-z)*hx + z*tanh(cand)
template <int MODE>
__global__ __launch_bounds__(256)
void gemm_diff(const float* __restrict__ inputs,
               const float* __restrict__ hxlike,   // hx (pass A) or r*hx (pass B)
               const float* __restrict__ W1,
               const float* __restrict__ W2,
               const float* __restrict__ Wt,       // (NOUT, 384) row-major
               const float* __restrict__ bias,     // (NOUT)
               const float* __restrict__ hx,       // true hx
               const float* __restrict__ zbuf,     // MODE1: read z
               float* __restrict__ out0,           // MODE0: z ; MODE1: final out
               float* __restrict__ out1,           // MODE0: rh
               int Mchunk)                         // rows in this chunk
{
    const int NOUT = (MODE == 0) ? 128 : 64;
    const int TN = NOUT / 32;
    const int BM = 64, BK = 16;
    __shared__ float As[BM * 20];            // [row][kk], pitch 20 keeps 16B align
    __shared__ float Bs[BK * NOUT];          // [kk>>2][g][kk&3]

    int tid = threadIdx.x;
    int tx = tid & 31;
    int ty = tid >> 5;
    int row0 = ty * 8;
    long mbase = (long)blockIdx.x * BM;      // row index within this chunk

    float acc[8][TN];
#pragma unroll
    for (int r = 0; r < 8; r++)
#pragma unroll
        for (int c = 0; c < TN; c++) acc[r][c] = 0.f;

    for (int k0 = 0; k0 < FDIM; k0 += BK) {
        // segment select (wave-uniform; boundaries 64/128/256 are BK-aligned)
        const float* src; int stride; int koff;
        if      (k0 < 64)  { src = inputs; stride = 64;  koff = 0;   }
        else if (k0 < 128) { src = hxlike; stride = 64;  koff = 64;  }
        else if (k0 < 256) { src = W1;     stride = 128; koff = 128; }
        else               { src = W2;     stride = 128; koff = 256; }
        // A tile: 64 rows x 16 k  (clamp OOB rows to a valid row)
        {
            int kk = tid & 15;
            int r = tid >> 4;                 // 0..15
#pragma unroll
            for (int p = 0; p < 4; p++) {
                int rr = r + p * 16;
                long row = mbase + rr;
                if (row >= Mchunk) row = Mchunk - 1;
                As[rr * 20 + kk] = src[row * (long)stride + (k0 - koff) + kk];
            }
        }
        // B tile: Wt[g*384 + k0+kk] -> Bs[(kk>>2)*NOUT*4 + g*4 + (kk&3)]
        {
            const int TOT = BK * NOUT;
            for (int l = tid; l < TOT; l += 256) {
                int kk = l & 15;
                int g  = l >> 4;
                Bs[(kk >> 2) * NOUT * 4 + g * 4 + (kk & 3)] = Wt[g * 384 + k0 + kk];
            }
        }
        __syncthreads();
#pragma unroll
        for (int k4 = 0; k4 < 4; k4++) {
            float4 breg[TN];
#pragma unroll
            for (int c = 0; c < TN; c++)      // g = tx + 32c: conflict-free
                breg[c] = *reinterpret_cast<const float4*>(&Bs[k4 * NOUT * 4 + (tx + c * 32) * 4]);
#pragma unroll
            for (int r = 0; r < 8; r++) {
                float4 a = *reinterpret_cast<const float4*>(&As[(row0 + r) * 20 + k4 * 4]);
#pragma unroll
                for (int c = 0; c < TN; c++) {
                    acc[r][c] += a.x * breg[c].x + a.y * breg[c].y
                               + a.z * breg[c].z + a.w * breg[c].w;
                }
            }
        }
        __syncthreads();
    }
    // epilogue
#pragma unroll
    for (int r = 0; r < 8; r++) {
        long m = mbase + row0 + r;
        if (m >= Mchunk) continue;
#pragma unroll
        for (int c = 0; c < TN; c++) {
            int g = tx + c * 32;
            float v = acc[r][c] + bias[g];
            if (MODE == 0) {
                float s = 1.f / (1.f + __expf(-v));
                if (g < 64) out0[m * 64 + g] = s;                          // z
                else        out1[m * 64 + (g - 64)] = s * hx[m * 64 + (g - 64)]; // r*hx
            } else {
                float cnd = tanhf(v);
                float zz = zbuf[m * 64 + g];
                out0[m * 64 + g] = (1.f - zz) * hx[m * 64 + g] + zz * cnd;
            }
        }
    }
}

// ---------------- launch ----------------

extern "C" void kernel_launch(void* const* d_in, const int* in_sizes, int n_in,
                              void* d_out, int out_size, void* d_ws, size_t ws_size,
                              hipStream_t stream) {
    const float* inputs = (const float*)d_in[0];
    const float* hx     = (const float*)d_in[1];
    const int*   ei     = (const int*)d_in[2];
    const float* ew     = (const float*)d_in[3];
    const float* wg     = (const float*)d_in[4];
    const float* wc     = (const float*)d_in[5];
    const float* bg     = (const float*)d_in[6];
    const float* bc     = (const float*)d_in[7];
    float* out = (float*)d_out;

    // CSR footprint
    const size_t csr_bytes = (size_t)(NN + 1) * 4 + (size_t)NN * 4 * 2
                           + (size_t)EE * 4 + (size_t)EE * 4 + 256;
    // per-batch intermediate footprint (fp32): W1(128)+W2(128)+z(64)+rh(64)
    const size_t per_batch = (size_t)NN * (128 + 128 + 64 + 64) * sizeof(float);

    // largest chunk (divides 32) that fits ws_size
    int bc_n = 1;
    const int cand[6] = {32, 16, 8, 4, 2, 1};
    for (int i = 0; i < 6; i++) {
        if (csr_bytes + (size_t)cand[i] * per_batch <= ws_size) { bc_n = cand[i]; break; }
    }

    // workspace layout (chunk-local buffers sized for bc_n batches)
    uint8_t* p = (uint8_t*)d_ws;
    float* W1   = (float*)p; p += (size_t)bc_n * NN * 128 * sizeof(float);
    float* W2   = (float*)p; p += (size_t)bc_n * NN * 128 * sizeof(float);
    float* zbuf = (float*)p; p += (size_t)bc_n * NN * 64 * sizeof(float);
    float* rh   = (float*)p; p += (size_t)bc_n * NN * 64 * sizeof(float);
    int* row_ptr = (int*)p;  p += (size_t)(NN + 1) * 4;
    int* counts  = (int*)p;  p += (size_t)NN * 4;
    int* cursor  = (int*)p;  p += (size_t)NN * 4;            // counts & cursor contiguous
    int* col_s   = (int*)p;  p += (size_t)EE * 4;
    float* w_s   = (float*)p;

    // CSR build (inputs re-restored every call -> rebuild every call)
    hipMemsetAsync(counts, 0, 2 * NN * sizeof(int), stream);
    count_kernel<<<(EE + 255) / 256, 256, 0, stream>>>(ei, counts);
    scan_kernel<<<1, 1024, 0, stream>>>(counts, row_ptr);
    fill_kernel<<<(EE + 255) / 256, 256, 0, stream>>>(ei, ew, row_ptr, cursor, col_s, w_s);

    for (int b0 = 0; b0 < BB; b0 += bc_n) {
        const float* in_c = inputs + (size_t)b0 * NN * 64;
        const float* hx_c = hx     + (size_t)b0 * NN * 64;
        float*       out_c = out   + (size_t)b0 * NN * 64;
        dim3 sg(NN / 2, bc_n);
        int Mchunk = bc_n * NN;
        int gemm_blocks = (Mchunk + 63) / 64;

        // Pass A: x0 = [inputs|hx]
        spmm_gather<<<sg, 256, 0, stream>>>(row_ptr, col_s, w_s, in_c, 64, hx_c, 64,
                                            nullptr, nullptr, 1.f, W1);
        spmm_gather<<<sg, 256, 0, stream>>>(row_ptr, col_s, w_s, W1, 128, W1 + 64, 128,
                                            in_c, hx_c, 2.f, W2);
        gemm_diff<0><<<gemm_blocks, 256, 0, stream>>>(in_c, hx_c, W1, W2, wg, bg, hx_c,
                                                      nullptr, zbuf, rh, Mchunk);
        // Pass B: x0' = [inputs|r*hx]
        spmm_gather<<<sg, 256, 0, stream>>>(row_ptr, col_s, w_s, in_c, 64, rh, 64,
                                            nullptr, nullptr, 1.f, W1);
        spmm_gather<<<sg, 256, 0, stream>>>(row_ptr, col_s, w_s, W1, 128, W1 + 64, 128,
                                            in_c, rh, 2.f, W2);
        gemm_diff<1><<<gemm_blocks, 256, 0, stream>>>(in_c, rh, W1, W2, wc, bc, hx_c,
                                                      zbuf, out_c, nullptr, Mchunk);
    }
}